// Round 1
// baseline (30142.859 us; speedup 1.0000x reference)
//
#include <hip/hip_runtime.h>
#include <hip/hip_bf16.h>

#define T_STEPS 256
#define BATCH 64
#define HID 512
#define NLAYERS 4
#define BT_GROUPS 4
#define GCOLS 64
#define SCAN_THREADS 192
#define ASTRIDE 1032   // padded LDS k-stride in elements (1024 + 8)

typedef __bf16 bf16_t;
typedef __attribute__((ext_vector_type(8))) __bf16 bf16x8;
typedef __attribute__((ext_vector_type(4))) float f32x4;

__device__ __forceinline__ float sigm(float x){ return 1.0f/(1.0f + __expf(-x)); }
__device__ __forceinline__ float tanh_f(float x){ return 2.0f/(1.0f + __expf(-2.0f*x)) - 1.0f; }
__device__ __forceinline__ unsigned short f2bf(float x){ __bf16 b=(__bf16)x; return __builtin_bit_cast(unsigned short, b); }

// ---- transpose fp32 [R][C] -> bf16 [C][R] ----
__global__ void transpose_cast_kernel(const float* __restrict__ src, unsigned short* __restrict__ dst, int R, int C){
  __shared__ float tile[32][33];
  int tx = threadIdx.x & 31, ty = threadIdx.x >> 5;
  int c0 = blockIdx.x*32, r0 = blockIdx.y*32;
  #pragma unroll
  for(int i=0;i<4;i++){ int r = r0 + ty + i*8; tile[ty+i*8][tx] = src[(size_t)r*C + c0 + tx]; }
  __syncthreads();
  #pragma unroll
  for(int i=0;i<4;i++){ int c = c0 + ty + i*8; dst[(size_t)c*R + r0 + tx] = f2bf(tile[tx][ty+i*8]); }
}

// ---- inputs (B,T,D) fp32 -> masked bf16 (T,B,D) ----
__global__ void prep_x0_kernel(const float* __restrict__ inp, const int* __restrict__ lens, unsigned short* __restrict__ x0){
  int idx = blockIdx.x*blockDim.x + threadIdx.x;
  int e = idx*4;
  int d = e & (HID-1);
  int tb = e >> 9;
  int b = tb & (BATCH-1);
  int t = tb >> 6;
  const float4 v = *(const float4*)(inp + ((size_t)b*T_STEPS + t)*HID + d);
  float m = (t < lens[b]) ? 1.f : 0.f;
  ushort4 u; u.x=f2bf(v.x*m); u.y=f2bf(v.y*m); u.z=f2bf(v.z*m); u.w=f2bf(v.w*m);
  *(ushort4*)(x0 + ((size_t)t*BATCH + b)*HID + d) = u;
}

// ---- fused per-layer scan ----
// block (bt,g): batch rows bt*16..+15, h-cols g*8..+7 (48 gate cols: i f gc o r lin)
__global__ void __launch_bounds__(SCAN_THREADS,1)
scan_kernel(const unsigned short* __restrict__ xsrc,
            const unsigned short* __restrict__ WihT,   // [3072][512] bf16
            const unsigned short* __restrict__ WhhT,   // [2560][512] bf16
            const float* __restrict__ bias_l,
            const int* __restrict__ lens,
            float* __restrict__ Hx,                    // [2][64][512] fp32
            int* __restrict__ flags,                   // [4][64]
            unsigned short* __restrict__ xdst,         // bf16 (T,B,H), null on last layer
            float* __restrict__ dout,                  // fp32 (B,T,H), last layer only
            int rev)
{
  extern __shared__ char smem[];
  unsigned short* Wl = (unsigned short*)smem;            // [48][ASTRIDE]
  unsigned short* Al = Wl + 48*ASTRIDE;                  // [16][ASTRIDE]
  float* gl = (float*)(Al + 16*ASTRIDE);                 // [16][52]
  float* cl = gl + 16*52;                                // [16][8]
  float* bl = cl + 128;                                  // [40]
  int*   ll = (int*)(bl + 40);                           // [16]

  const int tid = threadIdx.x;
  const int bt  = blockIdx.x & (BT_GROUPS-1);
  const int g   = blockIdx.x >> 2;

  // stage weight slice: cols c=0..47, q=c>>3 in {i,f,gc,o,r,lin}, gate col = q*512 + g*8 + (c&7)
  for(int idx=tid; idx<48*128; idx+=SCAN_THREADS){
    int c = idx >> 7, p4 = idx & 127;
    int q = c >> 3, j = c & 7;
    int srow = q*512 + g*8 + j;
    ushort4 v = ((const ushort4*)(WihT + (size_t)srow*HID))[p4];
    *(ushort4*)(Wl + c*ASTRIDE + p4*4) = v;
    ushort4 w;
    if(c < 40) w = ((const ushort4*)(WhhT + (size_t)srow*HID))[p4];
    else { w.x=0; w.y=0; w.z=0; w.w=0; }
    *(ushort4*)(Wl + c*ASTRIDE + 512 + p4*4) = w;
  }
  if(tid < 40) bl[tid] = bias_l[(tid>>3)*HID + g*8 + (tid&7)];
  if(tid < 16) ll[tid] = lens[bt*16 + tid];
  for(int i=tid;i<128;i+=SCAN_THREADS) cl[i]=0.f;
  __syncthreads();

  const int lane = tid & 63;
  const int wv   = tid >> 6;      // n-tile 0..2
  const int frow = lane & 15;
  const int quad = lane >> 4;

  for(int s=0; s<T_STEPS; s++){
    // stage h: Hx[s&1] fp32 -> bf16 into Al[:,512..1023]
    const float4* hsrc = (const float4*)(Hx + (size_t)(s&1)*BATCH*HID + (size_t)bt*16*HID);
    for(int idx=tid; idx<2048; idx+=SCAN_THREADS){
      int r = idx >> 7, c4 = idx & 127;
      float4 v = hsrc[idx];
      ushort4 u; u.x=f2bf(v.x); u.y=f2bf(v.y); u.z=f2bf(v.z); u.w=f2bf(v.w);
      *(ushort4*)(Al + r*ASTRIDE + 512 + c4*4) = u;
    }
    // stage x_t rows (per-row time index for reversed layers)
    for(int idx=tid; idx<2048; idx+=SCAN_THREADS){
      int r = idx >> 7, c4 = idx & 127;
      int L = ll[r];
      int t = rev ? ((s < L) ? (L-1-s) : s) : s;
      ushort4 v = ((const ushort4*)(xsrc + ((size_t)t*BATCH + bt*16 + r)*HID))[c4];
      *(ushort4*)(Al + r*ASTRIDE + c4*4) = v;
    }
    __syncthreads();

    // MFMA: [x_t | h] (16x1024) @ Wslice (1024x48), wave wv owns n-tile wv
    f32x4 acc0 = {0.f,0.f,0.f,0.f}, acc1 = {0.f,0.f,0.f,0.f};
    const bf16_t* arow = (const bf16_t*)Al + (size_t)frow*ASTRIDE + quad*8;
    const bf16_t* brow = (const bf16_t*)Wl + (size_t)(wv*16+frow)*ASTRIDE + quad*8;
    #pragma unroll
    for(int kk=0; kk<32; kk+=2){
      bf16x8 a0 = *(const bf16x8*)(arow + kk*32);
      bf16x8 b0 = *(const bf16x8*)(brow + kk*32);
      acc0 = __builtin_amdgcn_mfma_f32_16x16x32_bf16(a0,b0,acc0,0,0,0);
      bf16x8 a1 = *(const bf16x8*)(arow + kk*32+32);
      bf16x8 b1 = *(const bf16x8*)(brow + kk*32+32);
      acc1 = __builtin_amdgcn_mfma_f32_16x16x32_bf16(a1,b1,acc1,0,0,0);
    }
    f32x4 acc = acc0 + acc1;
    #pragma unroll
    for(int r4=0;r4<4;r4++) gl[(quad*4+r4)*52 + wv*16 + frow] = acc[r4];  // C: col=lane&15, row=quad*4+reg
    __syncthreads();

    // elementwise combine (fp32 c state)
    if(tid < 128){
      int r = tid >> 3, j = tid & 7;
      int L = ll[r];
      bool valid = s < L;
      float m = valid ? 1.f : 0.f;
      int t = rev ? (valid ? (L-1-s) : s) : s;
      const float* gr = gl + r*52;
      float gi = sigm(gr[j]      + bl[j]);
      float gf = sigm(gr[8+j]   + bl[8+j]);
      float gc = tanh_f(gr[16+j] + bl[16+j]);
      float go = sigm(gr[24+j]  + bl[24+j]);
      float grr= sigm(gr[32+j]  + bl[32+j]);
      float lin= gr[40+j];
      float cn = (gf*cl[tid] + gi*gc) * m;
      float hn = (grr*(go*tanh_f(cn)) + (1.f-grr)*lin) * m;
      cl[tid] = cn;
      int brow = bt*16 + r, hcol = g*8 + j;
      Hx[(size_t)((s+1)&1)*BATCH*HID + (size_t)brow*HID + hcol] = hn;
      if(dout) dout[((size_t)brow*T_STEPS + t)*HID + hcol] = hn;
      else     xdst[((size_t)t*BATCH + brow)*HID + hcol] = f2bf(hn);
    }

    // inter-block barrier among the 64 blocks of this batch-group
    __threadfence();
    __syncthreads();
    if(tid==0) __hip_atomic_store(&flags[bt*GCOLS + g], s+1, __ATOMIC_RELEASE, __HIP_MEMORY_SCOPE_AGENT);
    if(tid < 64){
      int it = 0; bool ok = false;
      do{
        int v = __hip_atomic_load(&flags[bt*GCOLS + lane], __ATOMIC_ACQUIRE, __HIP_MEMORY_SCOPE_AGENT);
        ok = v > s;
      } while(!__all(ok) && ++it < (1<<20));
    }
    __syncthreads();
  }
}

#define SMEM_BYTES (64*ASTRIDE*2 + 16*52*4 + 128*4 + 40*4 + 16*4)

extern "C" void kernel_launch(void* const* d_in, const int* in_sizes, int n_in,
                              void* d_out, int out_size, void* d_ws, size_t ws_size,
                              hipStream_t stream){
  const float* inp    = (const float*)d_in[0];
  const float* weight = (const float*)d_in[1];
  const float* bias   = (const float*)d_in[2];
  const int*   lens   = (const int*)d_in[3];
  float* dout = (float*)d_out;

  char* ws = (char*)d_ws;
  size_t off = 0;
  const size_t WTL = (size_t)(3072+2560)*512;   // per-layer transposed bf16 elements
  unsigned short* WT = (unsigned short*)(ws+off); off += (size_t)NLAYERS*WTL*2;
  unsigned short* x0 = (unsigned short*)(ws+off); off += (size_t)T_STEPS*BATCH*HID*2;
  unsigned short* xA = (unsigned short*)(ws+off); off += (size_t)T_STEPS*BATCH*HID*2;
  unsigned short* xB = (unsigned short*)(ws+off); off += (size_t)T_STEPS*BATCH*HID*2;
  float* Hx   = (float*)(ws+off); off += (size_t)2*BATCH*HID*4;
  int*   flags= (int*)(ws+off);   off += 1024;

  hipFuncSetAttribute((const void*)scan_kernel, hipFuncAttributeMaxDynamicSharedMemorySize, SMEM_BYTES);

  const size_t WS_L = (size_t)512*3072 + (size_t)512*2560; // per-layer fp32 weight elements
  for(int l=0;l<NLAYERS;l++){
    const float* wih = weight + l*WS_L;
    const float* whh = wih + (size_t)512*3072;
    unsigned short* wihT = WT + l*WTL;
    unsigned short* whhT = wihT + (size_t)3072*512;
    transpose_cast_kernel<<<dim3(3072/32,512/32),256,0,stream>>>(wih, wihT, 512, 3072);
    transpose_cast_kernel<<<dim3(2560/32,512/32),256,0,stream>>>(whh, whhT, 512, 2560);
  }
  prep_x0_kernel<<<8192,256,0,stream>>>(inp, lens, x0);

  unsigned short* bufs[4] = {x0, xA, xB, xA};
  for(int l=0;l<NLAYERS;l++){
    hipMemsetAsync(Hx, 0, (size_t)2*BATCH*HID*4 + 1024, stream);  // Hx + flags (adjacent)
    const unsigned short* xin = bufs[l];
    unsigned short* xout = (l<3) ? bufs[l+1] : nullptr;
    scan_kernel<<<256, SCAN_THREADS, SMEM_BYTES, stream>>>(
        xin, WT + l*WTL, WT + l*WTL + (size_t)3072*512,
        bias + (size_t)l*2560, lens, Hx, flags,
        xout, (l==3) ? dout : nullptr, l&1);
  }
}

// Round 2
// 19788.902 us; speedup vs baseline: 1.5232x; 1.5232x over previous
//
#include <hip/hip_runtime.h>
#include <hip/hip_bf16.h>

#define T_STEPS 256
#define BATCH 64
#define HID 512
#define NLAYERS 4
#define BT_GROUPS 4
#define GCOLS 64
#define SCAN_THREADS 192
#define ASTRIDE 1032   // padded LDS k-stride in elements (1024 + 8)

typedef __bf16 bf16_t;
typedef __attribute__((ext_vector_type(8))) __bf16 bf16x8;
typedef __attribute__((ext_vector_type(4))) float f32x4;

__device__ __forceinline__ float sigm(float x){ return 1.0f/(1.0f + __expf(-x)); }
__device__ __forceinline__ float tanh_f(float x){ return 2.0f/(1.0f + __expf(-2.0f*x)) - 1.0f; }
__device__ __forceinline__ unsigned short f2bf(float x){ __bf16 b=(__bf16)x; return __builtin_bit_cast(unsigned short, b); }

// ---- transpose fp32 [R][C] -> bf16 [C][R] ----
__global__ void transpose_cast_kernel(const float* __restrict__ src, unsigned short* __restrict__ dst, int R, int C){
  __shared__ float tile[32][33];
  int tx = threadIdx.x & 31, ty = threadIdx.x >> 5;
  int c0 = blockIdx.x*32, r0 = blockIdx.y*32;
  #pragma unroll
  for(int i=0;i<4;i++){ int r = r0 + ty + i*8; tile[ty+i*8][tx] = src[(size_t)r*C + c0 + tx]; }
  __syncthreads();
  #pragma unroll
  for(int i=0;i<4;i++){ int c = c0 + ty + i*8; dst[(size_t)c*R + r0 + tx] = f2bf(tile[tx][ty+i*8]); }
}

// ---- inputs (B,T,D) fp32 -> masked bf16 (T,B,D) ----
__global__ void prep_x0_kernel(const float* __restrict__ inp, const int* __restrict__ lens, unsigned short* __restrict__ x0){
  int idx = blockIdx.x*blockDim.x + threadIdx.x;
  int e = idx*4;
  int d = e & (HID-1);
  int tb = e >> 9;
  int b = tb & (BATCH-1);
  int t = tb >> 6;
  const float4 v = *(const float4*)(inp + ((size_t)b*T_STEPS + t)*HID + d);
  float m = (t < lens[b]) ? 1.f : 0.f;
  ushort4 u; u.x=f2bf(v.x*m); u.y=f2bf(v.y*m); u.z=f2bf(v.z*m); u.w=f2bf(v.w*m);
  *(ushort4*)(x0 + ((size_t)t*BATCH + b)*HID + d) = u;
}

// ---- fused per-layer scan ----
// block (bt,g): batch rows bt*16..+15, h-cols g*8..+7 (48 gate cols: i f gc o r lin)
__global__ void __launch_bounds__(SCAN_THREADS,1)
scan_kernel(const unsigned short* __restrict__ xsrc,
            const unsigned short* __restrict__ WihT,   // [3072][512] bf16
            const unsigned short* __restrict__ WhhT,   // [2560][512] bf16
            const float* __restrict__ bias_l,
            const int* __restrict__ lens,
            unsigned short* __restrict__ Hxb,          // [2][64][512] bf16
            int* __restrict__ flags,                   // arrival counter per bt at flags[bt*64]
            unsigned short* __restrict__ xdst,         // bf16 (T,B,H), null on last layer
            float* __restrict__ dout,                  // fp32 (B,T,H), last layer only
            int rev)
{
  extern __shared__ char smem[];
  unsigned short* Wl = (unsigned short*)smem;            // [48][ASTRIDE]
  unsigned short* Al = Wl + 48*ASTRIDE;                  // [16][ASTRIDE]
  float* gl = (float*)(Al + 16*ASTRIDE);                 // [16][52]
  float* cl = gl + 16*52;                                // [16][8]
  float* bl = cl + 128;                                  // [40]
  int*   ll = (int*)(bl + 40);                           // [16]

  const int tid = threadIdx.x;
  const int bt  = blockIdx.x & (BT_GROUPS-1);
  const int g   = blockIdx.x >> 2;

  // stage weight slice: cols c=0..47, q=c>>3 in {i,f,gc,o,r,lin}, gate col = q*512 + g*8 + (c&7)
  for(int idx=tid; idx<48*128; idx+=SCAN_THREADS){
    int c = idx >> 7, p4 = idx & 127;
    int q = c >> 3, j = c & 7;
    int srow = q*512 + g*8 + j;
    ushort4 v = ((const ushort4*)(WihT + (size_t)srow*HID))[p4];
    *(ushort4*)(Wl + c*ASTRIDE + p4*4) = v;
    ushort4 w;
    if(c < 40) w = ((const ushort4*)(WhhT + (size_t)srow*HID))[p4];
    else { w.x=0; w.y=0; w.z=0; w.w=0; }
    *(ushort4*)(Wl + c*ASTRIDE + 512 + p4*4) = w;
  }
  if(tid < 40) bl[tid] = bias_l[(tid>>3)*HID + g*8 + (tid&7)];
  if(tid < 16) ll[tid] = lens[bt*16 + tid];
  for(int i=tid;i<128;i+=SCAN_THREADS) cl[i]=0.f;
  __syncthreads();

  const int lane = tid & 63;
  const int wv   = tid >> 6;      // n-tile 0..2
  const int frow = lane & 15;
  const int quad = lane >> 4;
  int* cntp = flags + bt*64;

  for(int s=0; s<T_STEPS; s++){
    // stage x_t rows (per-row time index for reversed layers) -- no dependence on peers
    for(int idx=tid; idx<2048; idx+=SCAN_THREADS){
      int r = idx >> 7, c4 = idx & 127;
      int L = ll[r];
      int t = rev ? ((s < L) ? (L-1-s) : s) : s;
      ushort4 v = ((const ushort4*)(xsrc + ((size_t)t*BATCH + bt*16 + r)*HID))[c4];
      *(ushort4*)(Al + r*ASTRIDE + c4*4) = v;
    }
    __syncthreads();   // b1: x staged

    // x-part MFMAs (K = 0..511) -- overlaps with peers still finishing step s-1
    f32x4 acc0 = {0.f,0.f,0.f,0.f}, acc1 = {0.f,0.f,0.f,0.f};
    const bf16_t* arow = (const bf16_t*)Al + (size_t)frow*ASTRIDE + quad*8;
    const bf16_t* brow = (const bf16_t*)Wl + (size_t)(wv*16+frow)*ASTRIDE + quad*8;
    #pragma unroll
    for(int kk=0; kk<16; kk+=2){
      bf16x8 a0 = *(const bf16x8*)(arow + kk*32);
      bf16x8 b0 = *(const bf16x8*)(brow + kk*32);
      acc0 = __builtin_amdgcn_mfma_f32_16x16x32_bf16(a0,b0,acc0,0,0,0);
      bf16x8 a1 = *(const bf16x8*)(arow + kk*32+32);
      bf16x8 b1 = *(const bf16x8*)(brow + kk*32+32);
      acc1 = __builtin_amdgcn_mfma_f32_16x16x32_bf16(a1,b1,acc1,0,0,0);
    }

    // wait for h(s): all 64 group blocks arrived for step s-1. RELAXED polls, one acquire fence.
    if(s > 0){
      const int target = s*GCOLS;
      int it = 0;
      while(__hip_atomic_load(cntp, __ATOMIC_RELAXED, __HIP_MEMORY_SCOPE_AGENT) < target && ++it < 65536)
        __builtin_amdgcn_s_sleep(1);
      __builtin_amdgcn_fence(__ATOMIC_ACQUIRE, "agent");
    }

    // stage h (bf16, straight copy): Hxb[s&1] rows bt*16..+15 -> Al[:,512..1023]
    {
      const uint4* hsrc = (const uint4*)(Hxb + (size_t)(s&1)*BATCH*HID + (size_t)bt*16*HID);
      for(int idx=tid; idx<1024; idx+=SCAN_THREADS){
        int r = idx >> 6, c8 = idx & 63;
        *(uint4*)(Al + r*ASTRIDE + 512 + c8*8) = hsrc[idx];
      }
    }
    __syncthreads();  // b2: h staged

    // h-part MFMAs (K = 512..1023)
    #pragma unroll
    for(int kk=16; kk<32; kk+=2){
      bf16x8 a0 = *(const bf16x8*)(arow + kk*32);
      bf16x8 b0 = *(const bf16x8*)(brow + kk*32);
      acc0 = __builtin_amdgcn_mfma_f32_16x16x32_bf16(a0,b0,acc0,0,0,0);
      bf16x8 a1 = *(const bf16x8*)(arow + kk*32+32);
      bf16x8 b1 = *(const bf16x8*)(brow + kk*32+32);
      acc1 = __builtin_amdgcn_mfma_f32_16x16x32_bf16(a1,b1,acc1,0,0,0);
    }
    f32x4 acc = acc0 + acc1;
    #pragma unroll
    for(int r4=0;r4<4;r4++) gl[(quad*4+r4)*52 + wv*16 + frow] = acc[r4];  // C: col=lane&15, row=quad*4+reg
    __syncthreads();  // b3

    // elementwise combine (fp32 c state)
    if(tid < 128){
      int r = tid >> 3, j = tid & 7;
      int L = ll[r];
      bool valid = s < L;
      float m = valid ? 1.f : 0.f;
      int t = rev ? (valid ? (L-1-s) : s) : s;
      const float* gr = gl + r*52;
      float gi = sigm(gr[j]      + bl[j]);
      float gf = sigm(gr[8+j]   + bl[8+j]);
      float gc = tanh_f(gr[16+j] + bl[16+j]);
      float go = sigm(gr[24+j]  + bl[24+j]);
      float grr= sigm(gr[32+j]  + bl[32+j]);
      float lin= gr[40+j];
      float cn = (gf*cl[tid] + gi*gc) * m;
      float hn = (grr*(go*tanh_f(cn)) + (1.f-grr)*lin) * m;
      cl[tid] = cn;
      int brow = bt*16 + r, hcol = g*8 + j;
      Hxb[(size_t)((s+1)&1)*BATCH*HID + (size_t)brow*HID + hcol] = f2bf(hn);
      if(dout) dout[((size_t)brow*T_STEPS + t)*HID + hcol] = hn;
      else     xdst[((size_t)t*BATCH + brow)*HID + hcol] = f2bf(hn);
      __builtin_amdgcn_fence(__ATOMIC_RELEASE, "agent");  // waves 0,1: flush h stores (wave-uniform branch)
    }
    __syncthreads();  // b4: all flushes done before arrival

    if(tid == 0 && s+1 < T_STEPS)
      __hip_atomic_fetch_add(cntp, 1, __ATOMIC_RELAXED, __HIP_MEMORY_SCOPE_AGENT);
  }
}

#define SMEM_BYTES (64*ASTRIDE*2 + 16*52*4 + 128*4 + 40*4 + 16*4)

extern "C" void kernel_launch(void* const* d_in, const int* in_sizes, int n_in,
                              void* d_out, int out_size, void* d_ws, size_t ws_size,
                              hipStream_t stream){
  const float* inp    = (const float*)d_in[0];
  const float* weight = (const float*)d_in[1];
  const float* bias   = (const float*)d_in[2];
  const int*   lens   = (const int*)d_in[3];
  float* dout = (float*)d_out;

  char* ws = (char*)d_ws;
  size_t off = 0;
  const size_t WTL = (size_t)(3072+2560)*512;   // per-layer transposed bf16 elements
  unsigned short* WT = (unsigned short*)(ws+off); off += (size_t)NLAYERS*WTL*2;
  unsigned short* x0 = (unsigned short*)(ws+off); off += (size_t)T_STEPS*BATCH*HID*2;
  unsigned short* xA = (unsigned short*)(ws+off); off += (size_t)T_STEPS*BATCH*HID*2;
  unsigned short* xB = (unsigned short*)(ws+off); off += (size_t)T_STEPS*BATCH*HID*2;
  unsigned short* Hxb = (unsigned short*)(ws+off); off += (size_t)2*BATCH*HID*2;
  int*   flags= (int*)(ws+off);   off += 1024;

  hipFuncSetAttribute((const void*)scan_kernel, hipFuncAttributeMaxDynamicSharedMemorySize, SMEM_BYTES);

  const size_t WS_L = (size_t)512*3072 + (size_t)512*2560; // per-layer fp32 weight elements
  for(int l=0;l<NLAYERS;l++){
    const float* wih = weight + l*WS_L;
    const float* whh = wih + (size_t)512*3072;
    unsigned short* wihT = WT + l*WTL;
    unsigned short* whhT = wihT + (size_t)3072*512;
    transpose_cast_kernel<<<dim3(3072/32,512/32),256,0,stream>>>(wih, wihT, 512, 3072);
    transpose_cast_kernel<<<dim3(2560/32,512/32),256,0,stream>>>(whh, whhT, 512, 2560);
  }
  prep_x0_kernel<<<8192,256,0,stream>>>(inp, lens, x0);

  unsigned short* bufs[4] = {x0, xA, xB, xA};
  for(int l=0;l<NLAYERS;l++){
    hipMemsetAsync(Hxb, 0, (size_t)2*BATCH*HID*2 + 1024, stream);  // Hxb + flags (adjacent)
    const unsigned short* xin = bufs[l];
    unsigned short* xout = (l<3) ? bufs[l+1] : nullptr;
    scan_kernel<<<256, SCAN_THREADS, SMEM_BYTES, stream>>>(
        xin, WT + l*WTL, WT + l*WTL + (size_t)3072*512,
        bias + (size_t)l*2560, lens, Hxb, flags,
        xout, (l==3) ? dout : nullptr, l&1);
  }
}

// Round 3
// 6953.712 us; speedup vs baseline: 4.3348x; 2.8458x over previous
//
#include <hip/hip_runtime.h>
#include <hip/hip_bf16.h>

#define T_STEPS 256
#define BATCH 64
#define HID 512
#define NLAYERS 4
#define BT_GROUPS 4
#define GCOLS 64
#define SCAN_THREADS 192
#define ASTRIDE 1032   // padded LDS k-stride in elements (1024 + 8)

typedef __bf16 bf16_t;
typedef __attribute__((ext_vector_type(8))) __bf16 bf16x8;
typedef __attribute__((ext_vector_type(4))) float f32x4;

__device__ __forceinline__ float sigm(float x){ return 1.0f/(1.0f + __expf(-x)); }
__device__ __forceinline__ float tanh_f(float x){ return 2.0f/(1.0f + __expf(-2.0f*x)) - 1.0f; }
__device__ __forceinline__ unsigned short f2bf(float x){ __bf16 b=(__bf16)x; return __builtin_bit_cast(unsigned short, b); }

// ---- transpose fp32 [R][C] -> bf16 [C][R] ----
__global__ void transpose_cast_kernel(const float* __restrict__ src, unsigned short* __restrict__ dst, int R, int C){
  __shared__ float tile[32][33];
  int tx = threadIdx.x & 31, ty = threadIdx.x >> 5;
  int c0 = blockIdx.x*32, r0 = blockIdx.y*32;
  #pragma unroll
  for(int i=0;i<4;i++){ int r = r0 + ty + i*8; tile[ty+i*8][tx] = src[(size_t)r*C + c0 + tx]; }
  __syncthreads();
  #pragma unroll
  for(int i=0;i<4;i++){ int c = c0 + ty + i*8; dst[(size_t)c*R + r0 + tx] = f2bf(tile[tx][ty+i*8]); }
}

// ---- inputs (B,T,D) fp32 -> masked bf16 (T,B,D) ----
__global__ void prep_x0_kernel(const float* __restrict__ inp, const int* __restrict__ lens, unsigned short* __restrict__ x0){
  int idx = blockIdx.x*blockDim.x + threadIdx.x;
  int e = idx*4;
  int d = e & (HID-1);
  int tb = e >> 9;
  int b = tb & (BATCH-1);
  int t = tb >> 6;
  const float4 v = *(const float4*)(inp + ((size_t)b*T_STEPS + t)*HID + d);
  float m = (t < lens[b]) ? 1.f : 0.f;
  ushort4 u; u.x=f2bf(v.x*m); u.y=f2bf(v.y*m); u.z=f2bf(v.z*m); u.w=f2bf(v.w*m);
  *(ushort4*)(x0 + ((size_t)t*BATCH + b)*HID + d) = u;
}

// ---- fused per-layer scan ----
// block (bt,g): batch rows bt*16..+15, h-cols g*8..+7 (48 gate cols: i f gc o r lin)
// h exchange via agent-scope relaxed atomics (sc1, IC-coherent) -- NO fences, no L2 inv/wb.
__global__ void __launch_bounds__(SCAN_THREADS,1)
scan_kernel(const unsigned short* __restrict__ xsrc,
            const unsigned short* __restrict__ WihT,   // [3072][512] bf16
            const unsigned short* __restrict__ WhhT,   // [2560][512] bf16
            const float* __restrict__ bias_l,
            const int* __restrict__ lens,
            unsigned short* __restrict__ Hxb,          // [2][64][512] bf16
            int* __restrict__ flags,                   // arrival counter per bt at flags[bt*64]
            unsigned short* __restrict__ xdst,         // bf16 (T,B,H), null on last layer
            float* __restrict__ dout,                  // fp32 (B,T,H), last layer only
            int rev)
{
  extern __shared__ char smem[];
  unsigned short* Wl = (unsigned short*)smem;            // [48][ASTRIDE]
  unsigned short* Al = Wl + 48*ASTRIDE;                  // [16][ASTRIDE]
  float* gl = (float*)(Al + 16*ASTRIDE);                 // [16][52]
  float* cl = gl + 16*52;                                // [16][8]
  float* bl = cl + 128;                                  // [40]
  int*   ll = (int*)(bl + 40);                           // [16]
  unsigned short* hl = (unsigned short*)(ll + 16);       // [128] (8B aligned)

  const int tid = threadIdx.x;
  const int bt  = blockIdx.x & (BT_GROUPS-1);
  const int g   = blockIdx.x >> 2;

  // stage weight slice: cols c=0..47, q=c>>3 in {i,f,gc,o,r,lin}, gate col = q*512 + g*8 + (c&7)
  for(int idx=tid; idx<48*128; idx+=SCAN_THREADS){
    int c = idx >> 7, p4 = idx & 127;
    int q = c >> 3, j = c & 7;
    int srow = q*512 + g*8 + j;
    ushort4 v = ((const ushort4*)(WihT + (size_t)srow*HID))[p4];
    *(ushort4*)(Wl + c*ASTRIDE + p4*4) = v;
    ushort4 w;
    if(c < 40) w = ((const ushort4*)(WhhT + (size_t)srow*HID))[p4];
    else { w.x=0; w.y=0; w.z=0; w.w=0; }
    *(ushort4*)(Wl + c*ASTRIDE + 512 + p4*4) = w;
  }
  if(tid < 40) bl[tid] = bias_l[(tid>>3)*HID + g*8 + (tid&7)];
  if(tid < 16) ll[tid] = lens[bt*16 + tid];
  for(int i=tid;i<128;i+=SCAN_THREADS) cl[i]=0.f;
  __syncthreads();

  const int lane = tid & 63;
  const int wv   = tid >> 6;      // n-tile 0..2
  const int frow = lane & 15;
  const int quad = lane >> 4;
  int* cntp = flags + bt*64;

  for(int s=0; s<T_STEPS; s++){
    // stage x_t rows (per-row time index for reversed layers) -- no dependence on peers
    for(int idx=tid; idx<1024; idx+=SCAN_THREADS){
      int r = idx >> 6, c8 = idx & 63;
      int L = ll[r];
      int t = rev ? ((s < L) ? (L-1-s) : s) : s;
      uint4 v = ((const uint4*)(xsrc + ((size_t)t*BATCH + bt*16 + r)*HID))[c8];
      *(uint4*)(Al + r*ASTRIDE + c8*8) = v;
    }
    __syncthreads();   // b1: x staged

    // x-part MFMAs (K = 0..511) -- overlaps with peers still finishing step s-1
    f32x4 acc0 = {0.f,0.f,0.f,0.f}, acc1 = {0.f,0.f,0.f,0.f};
    const bf16_t* arow = (const bf16_t*)Al + (size_t)frow*ASTRIDE + quad*8;
    const bf16_t* brow = (const bf16_t*)Wl + (size_t)(wv*16+frow)*ASTRIDE + quad*8;
    #pragma unroll
    for(int kk=0; kk<16; kk+=2){
      bf16x8 a0 = *(const bf16x8*)(arow + kk*32);
      bf16x8 b0 = *(const bf16x8*)(brow + kk*32);
      acc0 = __builtin_amdgcn_mfma_f32_16x16x32_bf16(a0,b0,acc0,0,0,0);
      bf16x8 a1 = *(const bf16x8*)(arow + kk*32+32);
      bf16x8 b1 = *(const bf16x8*)(brow + kk*32+32);
      acc1 = __builtin_amdgcn_mfma_f32_16x16x32_bf16(a1,b1,acc1,0,0,0);
    }

    // wait for h(s): all 64 group blocks arrived for step s-1. RELAXED polls only.
    if(s > 0){
      const int target = s*GCOLS;
      int it = 0;
      while(__hip_atomic_load(cntp, __ATOMIC_RELAXED, __HIP_MEMORY_SCOPE_AGENT) < target && ++it < (1<<18)) {}
      asm volatile("" ::: "memory");
    }

    // stage h via coherent (sc1) 8B atomic loads: Hxb[s&1] rows bt*16..+15 -> Al[:,512..1023]
    {
      const unsigned long long* hsrc = (const unsigned long long*)(Hxb + (size_t)(s&1)*BATCH*HID + (size_t)bt*16*HID);
      for(int idx=tid; idx<2048; idx+=SCAN_THREADS){
        int r = idx >> 7, c4 = idx & 127;
        unsigned long long v = __hip_atomic_load(hsrc + idx, __ATOMIC_RELAXED, __HIP_MEMORY_SCOPE_AGENT);
        *(unsigned long long*)(Al + r*ASTRIDE + 512 + c4*4) = v;
      }
    }
    __syncthreads();  // b2: h staged

    // h-part MFMAs (K = 512..1023)
    #pragma unroll
    for(int kk=16; kk<32; kk+=2){
      bf16x8 a0 = *(const bf16x8*)(arow + kk*32);
      bf16x8 b0 = *(const bf16x8*)(brow + kk*32);
      acc0 = __builtin_amdgcn_mfma_f32_16x16x32_bf16(a0,b0,acc0,0,0,0);
      bf16x8 a1 = *(const bf16x8*)(arow + kk*32+32);
      bf16x8 b1 = *(const bf16x8*)(brow + kk*32+32);
      acc1 = __builtin_amdgcn_mfma_f32_16x16x32_bf16(a1,b1,acc1,0,0,0);
    }
    f32x4 acc = acc0 + acc1;
    #pragma unroll
    for(int r4=0;r4<4;r4++) gl[(quad*4+r4)*52 + wv*16 + frow] = acc[r4];  // C: col=lane&15, row=quad*4+reg
    __syncthreads();  // b3

    // elementwise combine (fp32 c state)
    if(tid < 128){
      int r = tid >> 3, j = tid & 7;
      int L = ll[r];
      bool valid = s < L;
      float m = valid ? 1.f : 0.f;
      int t = rev ? (valid ? (L-1-s) : s) : s;
      const float* gr = gl + r*52;
      float gi = sigm(gr[j]      + bl[j]);
      float gf = sigm(gr[8+j]   + bl[8+j]);
      float gc = tanh_f(gr[16+j] + bl[16+j]);
      float go = sigm(gr[24+j]  + bl[24+j]);
      float grr= sigm(gr[32+j]  + bl[32+j]);
      float lin= gr[40+j];
      float cn = (gf*cl[tid] + gi*gc) * m;
      float hn = (grr*(go*tanh_f(cn)) + (1.f-grr)*lin) * m;
      cl[tid] = cn;
      hl[tid] = f2bf(hn);
      int brow = bt*16 + r, hcol = g*8 + j;
      if(dout) dout[((size_t)brow*T_STEPS + t)*HID + hcol] = hn;
      else     xdst[((size_t)t*BATCH + brow)*HID + hcol] = f2bf(hn);
    }
    __syncthreads();  // b4: hl complete

    // wave 0: publish h via coherent (sc1) atomic stores, wave-wide vmcnt drain, then arrive
    if(tid < 32){
      int r = tid >> 1, cg = tid & 1;
      unsigned long long v = *(unsigned long long*)(hl + tid*4);
      unsigned long long* dst = (unsigned long long*)(Hxb + (size_t)((s+1)&1)*BATCH*HID
                                  + (size_t)(bt*16 + r)*HID + g*8 + cg*4);
      __hip_atomic_store(dst, v, __ATOMIC_RELAXED, __HIP_MEMORY_SCOPE_AGENT);
    }
    if(tid < 64){
      asm volatile("s_waitcnt vmcnt(0)" ::: "memory");   // wave-wide: all 32 lanes' stores at IC
      if(tid == 0 && s+1 < T_STEPS)
        __hip_atomic_fetch_add(cntp, 1, __ATOMIC_RELAXED, __HIP_MEMORY_SCOPE_AGENT);
    }
  }
}

#define SMEM_BYTES (64*ASTRIDE*2 + 16*52*4 + 128*4 + 40*4 + 16*4 + 128*2)

extern "C" void kernel_launch(void* const* d_in, const int* in_sizes, int n_in,
                              void* d_out, int out_size, void* d_ws, size_t ws_size,
                              hipStream_t stream){
  const float* inp    = (const float*)d_in[0];
  const float* weight = (const float*)d_in[1];
  const float* bias   = (const float*)d_in[2];
  const int*   lens   = (const int*)d_in[3];
  float* dout = (float*)d_out;

  char* ws = (char*)d_ws;
  size_t off = 0;
  const size_t WTL = (size_t)(3072+2560)*512;   // per-layer transposed bf16 elements
  unsigned short* WT = (unsigned short*)(ws+off); off += (size_t)NLAYERS*WTL*2;
  unsigned short* x0 = (unsigned short*)(ws+off); off += (size_t)T_STEPS*BATCH*HID*2;
  unsigned short* xA = (unsigned short*)(ws+off); off += (size_t)T_STEPS*BATCH*HID*2;
  unsigned short* xB = (unsigned short*)(ws+off); off += (size_t)T_STEPS*BATCH*HID*2;
  unsigned short* Hxb = (unsigned short*)(ws+off); off += (size_t)2*BATCH*HID*2;
  int*   flags= (int*)(ws+off);   off += 1024;

  hipFuncSetAttribute((const void*)scan_kernel, hipFuncAttributeMaxDynamicSharedMemorySize, SMEM_BYTES);

  const size_t WS_L = (size_t)512*3072 + (size_t)512*2560; // per-layer fp32 weight elements
  for(int l=0;l<NLAYERS;l++){
    const float* wih = weight + l*WS_L;
    const float* whh = wih + (size_t)512*3072;
    unsigned short* wihT = WT + l*WTL;
    unsigned short* whhT = wihT + (size_t)3072*512;
    transpose_cast_kernel<<<dim3(3072/32,512/32),256,0,stream>>>(wih, wihT, 512, 3072);
    transpose_cast_kernel<<<dim3(2560/32,512/32),256,0,stream>>>(whh, whhT, 512, 2560);
  }
  prep_x0_kernel<<<8192,256,0,stream>>>(inp, lens, x0);

  unsigned short* bufs[4] = {x0, xA, xB, xA};
  for(int l=0;l<NLAYERS;l++){
    hipMemsetAsync(Hxb, 0, (size_t)2*BATCH*HID*2 + 1024, stream);  // Hxb + flags (adjacent)
    const unsigned short* xin = bufs[l];
    unsigned short* xout = (l<3) ? bufs[l+1] : nullptr;
    scan_kernel<<<256, SCAN_THREADS, SMEM_BYTES, stream>>>(
        xin, WT + l*WTL, WT + l*WTL + (size_t)3072*512,
        bias + (size_t)l*2560, lens, Hxb, flags,
        xout, (l==3) ? dout : nullptr, l&1);
  }
}

// Round 4
// 3884.661 us; speedup vs baseline: 7.7595x; 1.7900x over previous
//
#include <hip/hip_runtime.h>
#include <hip/hip_bf16.h>

#define T_STEPS 256
#define BATCH 64
#define HID 512
#define NLAYERS 4
#define BT_GROUPS 4
#define GCOLS 64
#define SCAN_THREADS 192
#define ASTRIDE 1032   // padded LDS k-stride in elements (1024 + 8)

typedef __bf16 bf16_t;
typedef __attribute__((ext_vector_type(8))) __bf16 bf16x8;
typedef __attribute__((ext_vector_type(4))) float f32x4;

__device__ __forceinline__ float sigm(float x){ return 1.0f/(1.0f + __expf(-x)); }
__device__ __forceinline__ float tanh_f(float x){ return 2.0f/(1.0f + __expf(-2.0f*x)) - 1.0f; }
__device__ __forceinline__ unsigned short f2bf(float x){ __bf16 b=(__bf16)x; return __builtin_bit_cast(unsigned short, b); }

// ---- transpose fp32 [R][C] -> bf16 [C][R] ----
__global__ void transpose_cast_kernel(const float* __restrict__ src, unsigned short* __restrict__ dst, int R, int C){
  __shared__ float tile[32][33];
  int tx = threadIdx.x & 31, ty = threadIdx.x >> 5;
  int c0 = blockIdx.x*32, r0 = blockIdx.y*32;
  #pragma unroll
  for(int i=0;i<4;i++){ int r = r0 + ty + i*8; tile[ty+i*8][tx] = src[(size_t)r*C + c0 + tx]; }
  __syncthreads();
  #pragma unroll
  for(int i=0;i<4;i++){ int c = c0 + ty + i*8; dst[(size_t)c*R + r0 + tx] = f2bf(tile[tx][ty+i*8]); }
}

// ---- inputs (B,T,D) fp32 -> masked bf16 (T,B,D) ----
__global__ void prep_x0_kernel(const float* __restrict__ inp, const int* __restrict__ lens, unsigned short* __restrict__ x0){
  int idx = blockIdx.x*blockDim.x + threadIdx.x;
  int e = idx*4;
  int d = e & (HID-1);
  int tb = e >> 9;
  int b = tb & (BATCH-1);
  int t = tb >> 6;
  const float4 v = *(const float4*)(inp + ((size_t)b*T_STEPS + t)*HID + d);
  float m = (t < lens[b]) ? 1.f : 0.f;
  ushort4 u; u.x=f2bf(v.x*m); u.y=f2bf(v.y*m); u.z=f2bf(v.z*m); u.w=f2bf(v.w*m);
  *(ushort4*)(x0 + ((size_t)t*BATCH + b)*HID + d) = u;
}

// ---- fused per-layer scan ----
// block (bt,g): batch rows bt*16..+15, h-cols g*8..+7 (48 gate cols: i f gc o r lin)
// Software-pipelined: publish h(s-1) [wave0] || poll peers [wave1] || stage x [waves1,2]
// Flags: one 64B-padded slot per block, plain relaxed stores, 64-lane gather poll. No RMW.
__global__ void __launch_bounds__(SCAN_THREADS,1)
scan_kernel(const unsigned short* __restrict__ xsrc,
            const unsigned short* __restrict__ WihT,   // [3072][512] bf16
            const unsigned short* __restrict__ WhhT,   // [2560][512] bf16
            const float* __restrict__ bias_l,
            const int* __restrict__ lens,
            unsigned short* __restrict__ Hxb,          // [2][64][512] bf16
            int* __restrict__ flags,                   // [4][64] slots, 64B stride
            unsigned short* __restrict__ xdst,         // bf16 (T,B,H), null on last layer
            float* __restrict__ dout,                  // fp32 (B,T,H), last layer only
            int rev)
{
  extern __shared__ char smem[];
  unsigned short* Wl = (unsigned short*)smem;            // [48][ASTRIDE]
  unsigned short* Al = Wl + 48*ASTRIDE;                  // [16][ASTRIDE]
  float* gl = (float*)(Al + 16*ASTRIDE);                 // [16][52]
  float* bl = gl + 16*52;                                // [40]
  int*   ll = (int*)(bl + 40);                           // [16]

  const int tid = threadIdx.x;
  const int bt  = blockIdx.x & (BT_GROUPS-1);
  const int g   = blockIdx.x >> 2;

  // stage weight slice: cols c=0..47, q=c>>3, gate col = q*512 + g*8 + (c&7)
  for(int idx=tid; idx<48*128; idx+=SCAN_THREADS){
    int c = idx >> 7, p4 = idx & 127;
    int q = c >> 3, j = c & 7;
    int srow = q*512 + g*8 + j;
    ushort4 v = ((const ushort4*)(WihT + (size_t)srow*HID))[p4];
    *(ushort4*)(Wl + c*ASTRIDE + p4*4) = v;
    ushort4 w;
    if(c < 40) w = ((const ushort4*)(WhhT + (size_t)srow*HID))[p4];
    else { w.x=0; w.y=0; w.z=0; w.w=0; }
    *(ushort4*)(Wl + c*ASTRIDE + 512 + p4*4) = w;
  }
  if(tid < 40) bl[tid] = bias_l[(tid>>3)*HID + g*8 + (tid&7)];
  if(tid < 16) ll[tid] = lens[bt*16 + tid];
  __syncthreads();

  const int lane = tid & 63;
  const int wv   = tid >> 6;      // wave 0: combine/publish; wave 1: poll+stage; wave 2: stage
  const int frow = lane & 15;
  const int quad = lane >> 4;

  const bf16_t* arow = (const bf16_t*)Al + (size_t)frow*ASTRIDE + quad*8;
  const bf16_t* brow = (const bf16_t*)Wl + (size_t)(wv*16+frow)*ASTRIDE + quad*8;
  int* flagbase = flags + bt*GCOLS*16;   // 16 ints (64B) per slot

  // wave-0 combine-thread state
  const int cr  = lane >> 2;         // row 0..15
  const int jj  = (lane & 3)*2;      // col pair 0,2,4,6
  const int brow_g = bt*16 + cr;
  const int hcol   = g*8 + jj;
  float c0=0.f, c1=0.f;
  float bq[10];
  int L_r = 0;
  if(wv==0){
    L_r = ll[cr];
    #pragma unroll
    for(int q=0;q<5;q++){ bq[2*q] = bl[q*8+jj]; bq[2*q+1] = bl[q*8+jj+1]; }
  }
  unsigned int hpack = 0; float h0s=0.f, h1s=0.f; int tprev = 0;

  // waves 1,2: precompute x staging row/addr constants (8 items each thread)
  int  xL[8]; size_t xoff[8]; unsigned xldst[8];
  if(wv){
    int base = tid - 64;  // 0..127
    #pragma unroll
    for(int i=0;i<8;i++){
      int idx = base + i*128;      // 0..1023
      int r2 = idx >> 6, c8 = idx & 63;
      xL[i] = ll[r2];
      xoff[i] = (size_t)(bt*16 + r2)*HID + c8*8;
      xldst[i] = r2*ASTRIDE + c8*8;
    }
  }

  for(int s=0; s<T_STEPS; s++){
    // ---- phase 1 (concurrent): publish h(s-1) | poll peers | stage x(s) ----
    if(wv==0){
      if(s>0){
        unsigned int* dst = (unsigned int*)(Hxb + (size_t)(s&1)*BATCH*HID + (size_t)brow_g*HID + hcol);
        __hip_atomic_store(dst, hpack, __ATOMIC_RELAXED, __HIP_MEMORY_SCOPE_AGENT);
        asm volatile("s_waitcnt vmcnt(0)" ::: "memory");   // h at coherence point
        if(lane==0)
          __hip_atomic_store(flagbase + g*16, s, __ATOMIC_RELAXED, __HIP_MEMORY_SCOPE_AGENT);
        // outputs for step s-1 (fire-and-forget)
        if(dout) *(float2*)(dout + ((size_t)brow_g*T_STEPS + tprev)*HID + hcol) = make_float2(h0s,h1s);
        else     *(unsigned int*)(xdst + ((size_t)tprev*BATCH + brow_g)*HID + hcol) = hpack;
      }
    } else {
      uint4 xv[8];
      #pragma unroll
      for(int i=0;i<8;i++){
        int L = xL[i];
        int t = rev ? ((s < L) ? (L-1-s) : s) : s;
        xv[i] = *(const uint4*)(xsrc + (size_t)t*BATCH*HID + xoff[i]);
      }
      if(wv==1 && s>0){
        int* slot = flagbase + lane*16;
        int it = 0;
        while(1){
          int v = __hip_atomic_load(slot, __ATOMIC_RELAXED, __HIP_MEMORY_SCOPE_AGENT);
          if(__all(v >= s)) break;
          if(++it > (1<<20)) break;
        }
        asm volatile("" ::: "memory");
      }
      #pragma unroll
      for(int i=0;i<8;i++) *(uint4*)(Al + xldst[i]) = xv[i];
    }
    __syncthreads();   // b1: x staged, h(s) visible

    // ---- phase 2: h loads (regs) under x-MFMA shadow, then regs->LDS ----
    unsigned long long hv[11];
    const unsigned long long* hsrc = (const unsigned long long*)(Hxb + (size_t)(s&1)*BATCH*HID + (size_t)bt*16*HID);
    #pragma unroll
    for(int i=0;i<10;i++)
      hv[i] = __hip_atomic_load(hsrc + tid + i*192, __ATOMIC_RELAXED, __HIP_MEMORY_SCOPE_AGENT);
    if(tid < 128)
      hv[10] = __hip_atomic_load(hsrc + 1920 + tid, __ATOMIC_RELAXED, __HIP_MEMORY_SCOPE_AGENT);

    f32x4 acc0 = {0.f,0.f,0.f,0.f}, acc1 = {0.f,0.f,0.f,0.f};
    #pragma unroll
    for(int kk=0; kk<16; kk+=2){
      bf16x8 a0 = *(const bf16x8*)(arow + kk*32);
      bf16x8 b0 = *(const bf16x8*)(brow + kk*32);
      acc0 = __builtin_amdgcn_mfma_f32_16x16x32_bf16(a0,b0,acc0,0,0,0);
      bf16x8 a1 = *(const bf16x8*)(arow + kk*32+32);
      bf16x8 b1 = *(const bf16x8*)(brow + kk*32+32);
      acc1 = __builtin_amdgcn_mfma_f32_16x16x32_bf16(a1,b1,acc1,0,0,0);
    }

    #pragma unroll
    for(int i=0;i<10;i++){
      int idx = tid + i*192;
      *(unsigned long long*)(Al + (idx>>7)*ASTRIDE + 512 + (idx&127)*4) = hv[i];
    }
    if(tid < 128){
      int idx = 1920 + tid;
      *(unsigned long long*)(Al + (idx>>7)*ASTRIDE + 512 + (idx&127)*4) = hv[10];
    }
    __syncthreads();  // b2: h staged

    // ---- phase 3: h-MFMAs ----
    #pragma unroll
    for(int kk=16; kk<32; kk+=2){
      bf16x8 a0 = *(const bf16x8*)(arow + kk*32);
      bf16x8 b0 = *(const bf16x8*)(brow + kk*32);
      acc0 = __builtin_amdgcn_mfma_f32_16x16x32_bf16(a0,b0,acc0,0,0,0);
      bf16x8 a1 = *(const bf16x8*)(arow + kk*32+32);
      bf16x8 b1 = *(const bf16x8*)(brow + kk*32+32);
      acc1 = __builtin_amdgcn_mfma_f32_16x16x32_bf16(a1,b1,acc1,0,0,0);
    }
    f32x4 acc = acc0 + acc1;
    #pragma unroll
    for(int r4=0;r4<4;r4++) gl[(quad*4+r4)*52 + wv*16 + frow] = acc[r4];  // C: col=lane&15, row=quad*4+reg
    __syncthreads();  // b3

    // ---- phase 4: combine (wave 0 only; waves 1,2 proceed to next phase 1) ----
    if(wv==0){
      const float* gr = gl + cr*52;
      float2 gv0 = *(const float2*)(gr + jj);
      float2 gv1 = *(const float2*)(gr + 8  + jj);
      float2 gv2 = *(const float2*)(gr + 16 + jj);
      float2 gv3 = *(const float2*)(gr + 24 + jj);
      float2 gv4 = *(const float2*)(gr + 32 + jj);
      float2 gv5 = *(const float2*)(gr + 40 + jj);
      bool valid = s < L_r;
      float m = valid ? 1.f : 0.f;
      int t = rev ? (valid ? (L_r-1-s) : s) : s;
      float gi0 = sigm(gv0.x + bq[0]), gi1 = sigm(gv0.y + bq[1]);
      float gf0 = sigm(gv1.x + bq[2]), gf1 = sigm(gv1.y + bq[3]);
      float gc0 = tanh_f(gv2.x + bq[4]), gc1 = tanh_f(gv2.y + bq[5]);
      float go0 = sigm(gv3.x + bq[6]), go1 = sigm(gv3.y + bq[7]);
      float gr0 = sigm(gv4.x + bq[8]), gr1 = sigm(gv4.y + bq[9]);
      c0 = (gf0*c0 + gi0*gc0) * m;
      c1 = (gf1*c1 + gi1*gc1) * m;
      h0s = (gr0*(go0*tanh_f(c0)) + (1.f-gr0)*gv5.x) * m;
      h1s = (gr1*(go1*tanh_f(c1)) + (1.f-gr1)*gv5.y) * m;
      hpack = (unsigned int)f2bf(h0s) | ((unsigned int)f2bf(h1s) << 16);
      tprev = t;
    }
  }

  // epilogue: outputs for step T-1
  if(wv==0){
    if(dout) *(float2*)(dout + ((size_t)brow_g*T_STEPS + tprev)*HID + hcol) = make_float2(h0s,h1s);
    else     *(unsigned int*)(xdst + ((size_t)tprev*BATCH + brow_g)*HID + hcol) = hpack;
  }
}

#define SMEM_BYTES (64*ASTRIDE*2 + 16*52*4 + 40*4 + 16*4)

extern "C" void kernel_launch(void* const* d_in, const int* in_sizes, int n_in,
                              void* d_out, int out_size, void* d_ws, size_t ws_size,
                              hipStream_t stream){
  const float* inp    = (const float*)d_in[0];
  const float* weight = (const float*)d_in[1];
  const float* bias   = (const float*)d_in[2];
  const int*   lens   = (const int*)d_in[3];
  float* dout = (float*)d_out;

  char* ws = (char*)d_ws;
  size_t off = 0;
  const size_t WTL = (size_t)(3072+2560)*512;   // per-layer transposed bf16 elements
  unsigned short* WT = (unsigned short*)(ws+off); off += (size_t)NLAYERS*WTL*2;
  unsigned short* x0 = (unsigned short*)(ws+off); off += (size_t)T_STEPS*BATCH*HID*2;
  unsigned short* xA = (unsigned short*)(ws+off); off += (size_t)T_STEPS*BATCH*HID*2;
  unsigned short* xB = (unsigned short*)(ws+off); off += (size_t)T_STEPS*BATCH*HID*2;
  unsigned short* Hxb = (unsigned short*)(ws+off); off += (size_t)2*BATCH*HID*2;
  int*   flags= (int*)(ws+off);   off += BT_GROUPS*GCOLS*16*4;  // 64B-padded slots

  hipFuncSetAttribute((const void*)scan_kernel, hipFuncAttributeMaxDynamicSharedMemorySize, SMEM_BYTES);

  const size_t WS_L = (size_t)512*3072 + (size_t)512*2560; // per-layer fp32 weight elements
  for(int l=0;l<NLAYERS;l++){
    const float* wih = weight + l*WS_L;
    const float* whh = wih + (size_t)512*3072;
    unsigned short* wihT = WT + l*WTL;
    unsigned short* whhT = wihT + (size_t)3072*512;
    transpose_cast_kernel<<<dim3(3072/32,512/32),256,0,stream>>>(wih, wihT, 512, 3072);
    transpose_cast_kernel<<<dim3(2560/32,512/32),256,0,stream>>>(whh, whhT, 512, 2560);
  }
  prep_x0_kernel<<<8192,256,0,stream>>>(inp, lens, x0);

  unsigned short* bufs[4] = {x0, xA, xB, xA};
  for(int l=0;l<NLAYERS;l++){
    hipMemsetAsync(Hxb, 0, (size_t)2*BATCH*HID*2 + (size_t)BT_GROUPS*GCOLS*16*4, stream);  // Hxb + flags (adjacent)
    const unsigned short* xin = bufs[l];
    unsigned short* xout = (l<3) ? bufs[l+1] : nullptr;
    scan_kernel<<<256, SCAN_THREADS, SMEM_BYTES, stream>>>(
        xin, WT + l*WTL, WT + l*WTL + (size_t)3072*512,
        bias + (size_t)l*2560, lens, Hxb, flags,
        xout, (l==3) ? dout : nullptr, l&1);
  }
}